// Round 7
// baseline (500.789 us; speedup 1.0000x reference)
//
#include <hip/hip_runtime.h>

// ---------------------------------------------------------------------------
// GAT encoder, 2 layers, MI355X — round 7.
// Dtype-adaptive (probe: f32-vs-bf16 floats, i64-vs-i32 indices).
// bf16 internal, f32 accumulation, direct-sum softmax (logits bounded).
// CSR: bucket sort (pass1 fused w/ prep; pass2 fused w/ gemm1).
// gat_node1: TWO sequential channel-half passes -> gather footprint/pass
//   12.8 MB -> per-XCD L2 reuse distance ~1.6MB < 4MB capacity -> L2 hits
//   (r6 showed node1 at the ~3.6TB/s L2-miss-traffic roofline w/ 399MB).
// 6 dispatches: probe, prep+bucket, gemm1+pass2, node1, gemm2, node2.
// ---------------------------------------------------------------------------

typedef __attribute__((ext_vector_type(8))) short short8;
typedef __attribute__((ext_vector_type(4))) float floatx4;

#define FIN 256
#define H1 4
#define CH 64
#define CAP 16384   // bucket capacity (avg fill 8.4K, sigma ~92)

__device__ __forceinline__ float bf2f(ushort u) {
    union { unsigned int i; float f; } v; v.i = ((unsigned int)u) << 16; return v.f;
}
__device__ __forceinline__ ushort f2bf(float f) {
    union { float f; unsigned int i; } v; v.f = f;
    unsigned int r = v.i + 0x7fffu + ((v.i >> 16) & 1u);  // RNE
    return (ushort)(r >> 16);
}
__device__ __forceinline__ float load_in(const void* p, int i, int f) {
    return f ? ((const float*)p)[i] : bf2f(((const ushort*)p)[i]);
}
__device__ __forceinline__ int load_idx(const void* p, long long i, int f64) {
    return f64 ? (int)((const long long*)p)[i] : ((const int*)p)[i];
}

// ---- dtype probe + bcnt zero ----------------------------------------------
__global__ __launch_bounds__(256) void probe_kernel(const ushort* __restrict__ x,
                                                    const int* __restrict__ ei,
                                                    int* __restrict__ flags,
                                                    int* __restrict__ bcnt) {
    __shared__ int s_nan, s_odd;
    int t = threadIdx.x;
    bcnt[t] = 0;
    if (t == 0) { s_nan = 0; s_odd = 0; }
    __syncthreads();
    int nanc = 0, oddc = 0;
    for (int i = t; i < 16384; i += 256) {
        ushort u = x[i];
        if (((u >> 7) & 0xFF) == 0xFF) nanc++;
    }
    for (int i = t; i < 2048; i += 256)
        if (ei[2 * i + 1] != 0) oddc++;
    if (nanc) atomicAdd(&s_nan, nanc);
    if (oddc) atomicAdd(&s_odd, oddc);
    __syncthreads();
    if (t == 0) {
        flags[0] = (s_nan >= 2) ? 1 : 0;  // 1 = floats are f32
        flags[1] = (s_odd == 0) ? 1 : 0;  // 1 = indices are int64
    }
}

// ---- fused: x convert (8/thr) | W transposes | CSR bucket pass 1 -----------
__global__ __launch_bounds__(256) void prep_bucket_kernel(
        const void* __restrict__ x, const void* __restrict__ W1,
        const void* __restrict__ W2, ushort* __restrict__ xb,
        ushort* __restrict__ Wt1, ushort* __restrict__ Wt2,
        const void* __restrict__ ei, int* __restrict__ bcnt,
        unsigned int* __restrict__ buckets,
        int E, int Etot, int Nn, const int* __restrict__ flags,
        int PB_conv, int PB_tr_end) {
    __shared__ int lcnt[256], lbase[256], lcur[256];
    int bid = blockIdx.x, t = threadIdx.x;
    int f = flags[0];
    if (bid < PB_conv) {                       // ---- x -> bf16, 8 elem/thread
        int i0 = bid * 2048 + t * 8;
        if (f) {
            float4 v0 = ((const float4*)x)[i0 / 4];
            float4 v1 = ((const float4*)x)[i0 / 4 + 1];
            ushort4 o0, o1;
            o0.x = f2bf(v0.x); o0.y = f2bf(v0.y); o0.z = f2bf(v0.z); o0.w = f2bf(v0.w);
            o1.x = f2bf(v1.x); o1.y = f2bf(v1.y); o1.z = f2bf(v1.z); o1.w = f2bf(v1.w);
            *(ushort4*)(xb + i0) = o0;
            *(ushort4*)(xb + i0 + 4) = o1;
        } else {
            *(uint4*)(xb + i0) = ((const uint4*)x)[i0 / 8];
        }
        return;
    }
    if (bid < PB_tr_end) {                     // ---- W1^T, W2^T
        int j = (bid - PB_conv) * 256 + t;
        if (j < FIN * FIN) {
            int n = j / FIN, k = j % FIN;
            Wt1[j] = f2bf(load_in(W1, k * FIN + n, f));
        } else {
            int jj = j - FIN * FIN;
            int n = jj / FIN, k = jj % FIN;
            Wt2[jj] = f2bf(load_in(W2, k * CH + n, f));
        }
        return;
    }
    // ---- CSR pass 1: bucket partition, 16 edges/thread (4096/block)
    lcnt[t] = 0; lcur[t] = 0;
    __syncthreads();
    int f64 = flags[1];
    int base = (bid - PB_tr_end) * 4096 + t;
    unsigned int val[16]; int bk[16]; bool ok[16];
#pragma unroll
    for (int j = 0; j < 16; ++j) {
        int e = base + j * 256;
        ok[j] = e < Etot;
        bk[j] = 0; val[j] = 0;
        if (ok[j]) {
            int s, d;
            if (e < E) {
                s = load_idx(ei, e, f64);
                d = load_idx(ei, (long long)E + e, f64);
            } else {
                s = d = e - E;   // self-loops appended
            }
            s = min(max(s, 0), Nn - 1);
            d = min(max(d, 0), Nn - 1);
            bk[j] = d >> 8;
            val[j] = ((unsigned int)s << 8) | (unsigned int)(d & 255);
            atomicAdd(&lcnt[bk[j]], 1);
        }
    }
    __syncthreads();
    if (lcnt[t] > 0) lbase[t] = atomicAdd(&bcnt[t], lcnt[t]);
    __syncthreads();
#pragma unroll
    for (int j = 0; j < 16; ++j) {
        if (ok[j]) {
            int p = lbase[bk[j]] + atomicAdd(&lcur[bk[j]], 1);
            if (p < CAP) buckets[(size_t)bk[j] * CAP + p] = val[j];
        }
    }
}

// ---- shared gemm core (MFMA bf16, alpha fused in epilogue) -----------------
__device__ __forceinline__ void gemm_core(const ushort* __restrict__ A,
                                          const ushort* __restrict__ Bt,
                                          ushort* __restrict__ C,
                                          int M, int K, int Nc,
                                          const void* __restrict__ aS,
                                          const void* __restrict__ aD,
                                          float* __restrict__ alphaS,
                                          float* __restrict__ alphaD,
                                          int H, int f, int gx, int head) {
    int tid = threadIdx.x;
    int wave = tid >> 6, lane = tid & 63, quad = lane >> 4, l16 = lane & 15;
    int rbase = gx * 256 + wave * 64;
    int cbase = head * 64;
    floatx4 acc[4][4];
#pragma unroll
    for (int i = 0; i < 4; i++)
#pragma unroll
        for (int j = 0; j < 4; j++) acc[i][j] = (floatx4)0.f;

    for (int kb = 0; kb < K; kb += 32) {
        int k0 = kb + quad * 8;
        short8 a[4], b[4];
#pragma unroll
        for (int mt = 0; mt < 4; mt++) {
            int row = rbase + mt * 16 + l16;
            if (row >= M) row = M - 1;  // clamp; oob rows never stored
            a[mt] = *reinterpret_cast<const short8*>(A + (size_t)row * K + k0);
        }
#pragma unroll
        for (int nt = 0; nt < 4; nt++) {
            int col = cbase + nt * 16 + l16;
            b[nt] = *reinterpret_cast<const short8*>(Bt + (size_t)col * K + k0);
        }
#pragma unroll
        for (int mt = 0; mt < 4; mt++)
#pragma unroll
            for (int nt = 0; nt < 4; nt++)
                acc[mt][nt] = __builtin_amdgcn_mfma_f32_16x16x32_bf16(
                    a[mt], b[nt], acc[mt][nt], 0, 0, 0);
    }
    float asv[4], adv[4];
#pragma unroll
    for (int nt = 0; nt < 4; nt++) {
        int col = cbase + nt * 16 + l16;
        asv[nt] = load_in(aS, col, f);
        adv[nt] = load_in(aD, col, f);
    }
    // C/D layout: col = lane&15, row = quad*4 + reg   [m89-verified]
#pragma unroll
    for (int mt = 0; mt < 4; mt++) {
#pragma unroll
        for (int r = 0; r < 4; r++) {
            int row = rbase + mt * 16 + quad * 4 + r;
            float ps = 0.f, pd = 0.f;
#pragma unroll
            for (int nt = 0; nt < 4; nt++) {
                float w = acc[mt][nt][r];
                ps += w * asv[nt];
                pd += w * adv[nt];
            }
#pragma unroll
            for (int off = 8; off > 0; off >>= 1) {  // reduce over 16 col-lanes
                ps += __shfl_xor(ps, off, 16);
                pd += __shfl_xor(pd, off, 16);
            }
            if (row < M) {
                if (l16 == 0) {
                    alphaS[row * H + head] = ps;
                    alphaD[row * H + head] = pd;
                }
#pragma unroll
                for (int nt = 0; nt < 4; nt++) {
                    int col = cbase + nt * 16 + l16;
                    C[(size_t)row * Nc + col] = f2bf(acc[mt][nt][r]);
                }
            }
        }
    }
}

// ---- fused: gemm1 blocks [0, g1) + CSR pass-2 blocks [g1, g1+NB) -----------
__global__ __launch_bounds__(256) void gemm1_pass2_kernel(
        const ushort* __restrict__ A, const ushort* __restrict__ Bt,
        ushort* __restrict__ C, int M, int K, int Nc,
        const void* __restrict__ aS, const void* __restrict__ aD,
        float* __restrict__ alphaS, float* __restrict__ alphaD,
        const int* __restrict__ flags, int g1, int nbx,
        const int* __restrict__ bcnt, const unsigned int* __restrict__ buckets,
        int* __restrict__ offs, int* __restrict__ csr_src, int Nn) {
    __shared__ int part[256], sc[256], cur[256];
    int bid = blockIdx.x;
    int t = threadIdx.x;
    if (bid < g1) {
        gemm_core(A, Bt, C, M, K, Nc, aS, aD, alphaS, alphaD, 4, flags[0],
                  bid % nbx, bid / nbx);
        return;
    }
    // ---- CSR pass 2: one block per 256-node bucket ----
    int b = bid - g1;
    part[t] = bcnt[t];
    __syncthreads();
#pragma unroll
    for (int off = 1; off < 256; off <<= 1) {   // inclusive scan of bucket sizes
        int v = (t >= off) ? part[t - off] : 0;
        __syncthreads();
        part[t] += v;
        __syncthreads();
    }
    int basepos = (b == 0) ? 0 : part[b - 1];
    int nEdges = min(bcnt[b], CAP);
    sc[t] = 0;
    __syncthreads();
    const unsigned int* bk = buckets + (size_t)b * CAP;
    for (int i = t; i < nEdges; i += 256)
        atomicAdd(&sc[bk[i] & 255], 1);
    __syncthreads();
    int mycount = sc[t];
    __syncthreads();
#pragma unroll
    for (int off = 1; off < 256; off <<= 1) {   // inclusive scan of node counts
        int v = (t >= off) ? sc[t - off] : 0;
        __syncthreads();
        sc[t] += v;
        __syncthreads();
    }
    int excl = sc[t] - mycount;
    int gnode = b * 256 + t;
    if (gnode <= Nn) offs[gnode] = basepos + excl;
    cur[t] = excl;
    __syncthreads();
    for (int i = t; i < nEdges; i += 256) {
        unsigned int v = bk[i];
        int p = atomicAdd(&cur[v & 255], 1);
        csr_src[basepos + p] = (int)(v >> 8);
    }
}

// ---- layer-2 gemm (H=1), standalone ---------------------------------------
__global__ __launch_bounds__(256) void gemm2_kernel(const ushort* __restrict__ A,
                                                    const ushort* __restrict__ Bt,
                                                    ushort* __restrict__ C,
                                                    int M, int K, int Nc,
                                                    const void* __restrict__ aS,
                                                    const void* __restrict__ aD,
                                                    float* __restrict__ alphaS,
                                                    float* __restrict__ alphaD,
                                                    const int* __restrict__ flags) {
    gemm_core(A, Bt, C, M, K, Nc, aS, aD, alphaS, alphaD, 1, flags[0],
              blockIdx.x, blockIdx.y);
}

// ---- layer-1 aggregation: 1 wave/node, TWO channel-half passes -------------
// Pass P: lane covers 2 channels [P*32+(l16)*2, +2) of head (lane>>4).
// Footprint/pass = 12.8MB -> per-XCD L2 reuse distance ~1.6MB -> hits.
__global__ __launch_bounds__(256) void gat_node1(const int* __restrict__ csr_src,
                                                 const int* __restrict__ offs,
                                                 const float* __restrict__ asrc,
                                                 const float* __restrict__ adst,
                                                 const ushort* __restrict__ h1b,
                                                 const void* __restrict__ b1,
                                                 ushort* __restrict__ hmidb,
                                                 int Nn, const int* __restrict__ flags) {
    int f = flags[0];
    int wave = threadIdx.x >> 6, lane = threadIdx.x & 63;
    int n = blockIdx.x * 4 + wave;
    if (n >= Nn) return;
    int hh = lane >> 4, l16 = lane & 15;
    float ad = adst[n * H1 + hh];
    int beg = offs[n], end = offs[n + 1];

#pragma unroll
    for (int pass = 0; pass < 2; ++pass) {
        int rowoff = hh * 64 + pass * 32 + l16 * 2;   // ushort index in row
        float a0 = 0.f, a1 = 0.f, l = 0.f;
        int e = beg;
        while (e + 8 <= end) {
            int sj[8];
#pragma unroll
            for (int j = 0; j < 8; ++j) sj[j] = csr_src[e + j];
            float aj[8]; unsigned int vj[8];
#pragma unroll
            for (int j = 0; j < 8; ++j) {
                aj[j] = asrc[sj[j] * H1 + hh];
                vj[j] = *reinterpret_cast<const unsigned int*>(
                            h1b + (size_t)sj[j] * FIN + rowoff);
            }
#pragma unroll
            for (int j = 0; j < 8; ++j) {
                float s = aj[j] + ad;
                s = s > 0.f ? s : 0.2f * s;          // leaky_relu 0.2
                float p = __expf(s);
                l += p;
                union { unsigned int i; float fl; } c0, c1;
                c0.i = vj[j] << 16; c1.i = vj[j] & 0xffff0000u;
                a0 += p * c0.fl; a1 += p * c1.fl;
            }
            e += 8;
        }
        for (; e < end; ++e) {
            int src = csr_src[e];
            float s = asrc[src * H1 + hh] + ad;
            s = s > 0.f ? s : 0.2f * s;
            float p = __expf(s);
            l += p;
            unsigned int v = *reinterpret_cast<const unsigned int*>(
                                 h1b + (size_t)src * FIN + rowoff);
            union { unsigned int i; float fl; } c0, c1;
            c0.i = v << 16; c1.i = v & 0xffff0000u;
            a0 += p * c0.fl; a1 += p * c1.fl;
        }
        float inv = 1.f / (l + 1e-16f);
        float o0 = a0 * inv + load_in(b1, rowoff, f);
        float o1 = a1 * inv + load_in(b1, rowoff + 1, f);
        o0 = o0 > 0.f ? o0 : __expf(o0) - 1.f;   // ELU
        o1 = o1 > 0.f ? o1 : __expf(o1) - 1.f;
        unsigned int st = (unsigned int)f2bf(o0) | ((unsigned int)f2bf(o1) << 16);
        *reinterpret_cast<unsigned int*>(hmidb + (size_t)n * FIN + rowoff) = st;
    }
}

// ---- layer-2 aggregation: 1 wave/node, 16-deep pipeline, lane = channel ----
__global__ __launch_bounds__(256) void gat_node2(const int* __restrict__ csr_src,
                                                 const int* __restrict__ offs,
                                                 const float* __restrict__ asrc,
                                                 const float* __restrict__ adst,
                                                 const ushort* __restrict__ h2b,
                                                 const void* __restrict__ b2,
                                                 void* __restrict__ out, int Nn,
                                                 const int* __restrict__ flags) {
    int f = flags[0];
    int wave = threadIdx.x >> 6, lane = threadIdx.x & 63;
    int n = blockIdx.x * 4 + wave;
    if (n >= Nn) return;
    float ad = adst[n];
    int beg = offs[n], end = offs[n + 1];
    float acc = 0.f, l = 0.f;

    int e = beg;
    while (e + 16 <= end) {
        int sj[16];
#pragma unroll
        for (int j = 0; j < 16; ++j) sj[j] = csr_src[e + j];
        float aj[16]; ushort vj[16];
#pragma unroll
        for (int j = 0; j < 16; ++j) {
            aj[j] = asrc[sj[j]];
            vj[j] = h2b[(size_t)sj[j] * CH + lane];
        }
#pragma unroll
        for (int j = 0; j < 16; ++j) {
            float s = aj[j] + ad;
            s = s > 0.f ? s : 0.2f * s;
            float p = __expf(s);
            l += p;
            acc += p * bf2f(vj[j]);
        }
        e += 16;
    }
    for (; e < end; ++e) {
        int src = csr_src[e];
        float s = asrc[src] + ad;
        s = s > 0.f ? s : 0.2f * s;
        float p = __expf(s);
        l += p;
        acc += p * bf2f(h2b[(size_t)src * CH + lane]);
    }
    float o = acc / (l + 1e-16f) + load_in(b2, lane, f);
    size_t oi = (size_t)n * CH + lane;
    if (f) ((float*)out)[oi] = o;
    else   ((ushort*)out)[oi] = f2bf(o);
}

extern "C" void kernel_launch(void* const* d_in, const int* in_sizes, int n_in,
                              void* d_out, int out_size, void* d_ws, size_t ws_size,
                              hipStream_t stream) {
    const void* x   = d_in[0];
    const void* ei  = d_in[1];
    const void* W1  = d_in[2];
    const void* as1 = d_in[3];
    const void* ad1 = d_in[4];
    const void* b1  = d_in[5];
    const void* W2  = d_in[6];
    const void* as2 = d_in[7];
    const void* ad2 = d_in[8];
    const void* b2  = d_in[9];

    const int Nn = in_sizes[0] / FIN;      // 50000
    const int E  = in_sizes[1] / 2;        // 1600000
    const int ET = E + Nn;
    const int NB = (Nn + 255) >> 8;        // 196 buckets

    char* ws = (char*)d_ws;
    size_t off = 0;
    auto alloc = [&](size_t bytes) {
        size_t o = off;
        off += (bytes + 255) & ~(size_t)255;
        return o;
    };
    ushort* xb    = (ushort*)(ws + alloc((size_t)Nn * FIN * 2));
    ushort* h1b   = (ushort*)(ws + alloc((size_t)Nn * FIN * 2));
    ushort* hmidb = (ushort*)(ws + alloc((size_t)Nn * FIN * 2));
    ushort* h2b   = (ushort*)(ws + alloc((size_t)Nn * CH * 2));
    ushort* Wt1   = (ushort*)(ws + alloc((size_t)FIN * FIN * 2));
    ushort* Wt2   = (ushort*)(ws + alloc((size_t)CH * FIN * 2));
    float* as1f   = (float*)(ws + alloc((size_t)Nn * H1 * 4));
    float* ad1f   = (float*)(ws + alloc((size_t)Nn * H1 * 4));
    float* as2f   = (float*)(ws + alloc((size_t)Nn * 4));
    float* ad2f   = (float*)(ws + alloc((size_t)Nn * 4));
    int*   offs   = (int*)(ws + alloc((size_t)(Nn + 1) * 4));
    int*   csr    = (int*)(ws + alloc((size_t)ET * 4));
    unsigned int* buckets = (unsigned int*)(ws + alloc((size_t)256 * CAP * 4));
    int*   bcnt   = (int*)(ws + alloc(256 * 4));
    int*   flags  = (int*)(ws + alloc(256));
    (void)ws_size; (void)n_in; (void)out_size;

    probe_kernel<<<1, 256, 0, stream>>>((const ushort*)x, (const int*)ei, flags, bcnt);

    // fused prep (convert+transpose) | bucket pass 1
    int PB_conv = (Nn * FIN) / 2048;                       // 8 elem/thread
    int PB_tr   = (FIN * FIN + CH * FIN) / 256;            // 320
    int PB_bkt  = (ET + 4095) / 4096;
    prep_bucket_kernel<<<PB_conv + PB_tr + PB_bkt, 256, 0, stream>>>(
        x, W1, W2, xb, Wt1, Wt2, ei, bcnt, buckets,
        E, ET, Nn, flags, PB_conv, PB_conv + PB_tr);

    // fused: gemm1 (+alpha) and CSR pass 2
    int nbx = (Nn + 255) / 256;            // 196 row-blocks
    int g1 = nbx * H1;                     // 784 gemm blocks
    gemm1_pass2_kernel<<<g1 + NB, 256, 0, stream>>>(
        xb, Wt1, h1b, Nn, FIN, FIN, as1, ad1, as1f, ad1f,
        flags, g1, nbx, bcnt, buckets, offs, csr, Nn);

    gat_node1<<<(Nn + 3) / 4, 256, 0, stream>>>(csr, offs, as1f, ad1f, h1b, b1, hmidb, Nn, flags);

    // layer 2
    gemm2_kernel<<<dim3((Nn + 255) / 256, 1), 256, 0, stream>>>(
        hmidb, Wt2, h2b, Nn, FIN, CH, as2, ad2, as2f, ad2f, flags);
    gat_node2<<<(Nn + 3) / 4, 256, 0, stream>>>(csr, offs, as2f, ad2f, h2b, b2, d_out, Nn, flags);
}

// Round 8
// 362.309 us; speedup vs baseline: 1.3822x; 1.3822x over previous
//
#include <hip/hip_runtime.h>

// ---------------------------------------------------------------------------
// GAT encoder, 2 layers, MI355X — round 8.
// Dtype-adaptive (probe: f32-vs-bf16 floats, i64-vs-i32 indices).
// bf16 internal, f32 accumulation, direct-sum softmax (logits bounded).
// CSR: bucket sort (pass1 fused w/ prep; pass2 fused w/ gemm1).
// h1 stored PLANAR: [plane][Nn][128ch]; node1 runs as TWO DISPATCHES (one per
// plane) -> hard time separation, 12.8MB footprint/pass -> L2-resident
// (r7 lesson: intra-kernel passes interleave across waves; only a dispatch
// boundary separates footprints -- r7 doubled FETCH to 792MB).
// node1: 2 edges/wave (halves per-edge issue cost, r6 measured 54 inst/edge).
// node2: 4 edges/wave. Masked tails via a=-1e30 -> p=0.
// 7 dispatches: probe, prep+bucket, gemm1+pass2, node1x2, gemm2, node2.
// ---------------------------------------------------------------------------

typedef __attribute__((ext_vector_type(8))) short short8;
typedef __attribute__((ext_vector_type(4))) float floatx4;

#define FIN 256
#define H1 4
#define CH 64
#define CAP 16384   // bucket capacity (avg fill 8.4K, sigma ~92)

__device__ __forceinline__ float bf2f(ushort u) {
    union { unsigned int i; float f; } v; v.i = ((unsigned int)u) << 16; return v.f;
}
__device__ __forceinline__ ushort f2bf(float f) {
    union { float f; unsigned int i; } v; v.f = f;
    unsigned int r = v.i + 0x7fffu + ((v.i >> 16) & 1u);  // RNE
    return (ushort)(r >> 16);
}
__device__ __forceinline__ float load_in(const void* p, int i, int f) {
    return f ? ((const float*)p)[i] : bf2f(((const ushort*)p)[i]);
}
__device__ __forceinline__ int load_idx(const void* p, long long i, int f64) {
    return f64 ? (int)((const long long*)p)[i] : ((const int*)p)[i];
}

// ---- dtype probe + bcnt zero ----------------------------------------------
__global__ __launch_bounds__(256) void probe_kernel(const ushort* __restrict__ x,
                                                    const int* __restrict__ ei,
                                                    int* __restrict__ flags,
                                                    int* __restrict__ bcnt) {
    __shared__ int s_nan, s_odd;
    int t = threadIdx.x;
    bcnt[t] = 0;
    if (t == 0) { s_nan = 0; s_odd = 0; }
    __syncthreads();
    int nanc = 0, oddc = 0;
    for (int i = t; i < 16384; i += 256) {
        ushort u = x[i];
        if (((u >> 7) & 0xFF) == 0xFF) nanc++;
    }
    for (int i = t; i < 2048; i += 256)
        if (ei[2 * i + 1] != 0) oddc++;
    if (nanc) atomicAdd(&s_nan, nanc);
    if (oddc) atomicAdd(&s_odd, oddc);
    __syncthreads();
    if (t == 0) {
        flags[0] = (s_nan >= 2) ? 1 : 0;  // 1 = floats are f32
        flags[1] = (s_odd == 0) ? 1 : 0;  // 1 = indices are int64
    }
}

// ---- fused: x convert (8/thr) | W transposes | CSR bucket pass 1 -----------
__global__ __launch_bounds__(256) void prep_bucket_kernel(
        const void* __restrict__ x, const void* __restrict__ W1,
        const void* __restrict__ W2, ushort* __restrict__ xb,
        ushort* __restrict__ Wt1, ushort* __restrict__ Wt2,
        const void* __restrict__ ei, int* __restrict__ bcnt,
        unsigned int* __restrict__ buckets,
        int E, int Etot, int Nn, const int* __restrict__ flags,
        int PB_conv, int PB_tr_end) {
    __shared__ int lcnt[256], lbase[256], lcur[256];
    int bid = blockIdx.x, t = threadIdx.x;
    int f = flags[0];
    if (bid < PB_conv) {                       // ---- x -> bf16, 8 elem/thread
        int i0 = bid * 2048 + t * 8;
        if (f) {
            float4 v0 = ((const float4*)x)[i0 / 4];
            float4 v1 = ((const float4*)x)[i0 / 4 + 1];
            ushort4 o0, o1;
            o0.x = f2bf(v0.x); o0.y = f2bf(v0.y); o0.z = f2bf(v0.z); o0.w = f2bf(v0.w);
            o1.x = f2bf(v1.x); o1.y = f2bf(v1.y); o1.z = f2bf(v1.z); o1.w = f2bf(v1.w);
            *(ushort4*)(xb + i0) = o0;
            *(ushort4*)(xb + i0 + 4) = o1;
        } else {
            *(uint4*)(xb + i0) = ((const uint4*)x)[i0 / 8];
        }
        return;
    }
    if (bid < PB_tr_end) {                     // ---- W1^T, W2^T
        int j = (bid - PB_conv) * 256 + t;
        if (j < FIN * FIN) {
            int n = j / FIN, k = j % FIN;
            Wt1[j] = f2bf(load_in(W1, k * FIN + n, f));
        } else {
            int jj = j - FIN * FIN;
            int n = jj / FIN, k = jj % FIN;
            Wt2[jj] = f2bf(load_in(W2, k * CH + n, f));
        }
        return;
    }
    // ---- CSR pass 1: bucket partition, 16 edges/thread (4096/block)
    lcnt[t] = 0; lcur[t] = 0;
    __syncthreads();
    int f64 = flags[1];
    int base = (bid - PB_tr_end) * 4096 + t;
    unsigned int val[16]; int bk[16]; bool ok[16];
#pragma unroll
    for (int j = 0; j < 16; ++j) {
        int e = base + j * 256;
        ok[j] = e < Etot;
        bk[j] = 0; val[j] = 0;
        if (ok[j]) {
            int s, d;
            if (e < E) {
                s = load_idx(ei, e, f64);
                d = load_idx(ei, (long long)E + e, f64);
            } else {
                s = d = e - E;   // self-loops appended
            }
            s = min(max(s, 0), Nn - 1);
            d = min(max(d, 0), Nn - 1);
            bk[j] = d >> 8;
            val[j] = ((unsigned int)s << 8) | (unsigned int)(d & 255);
            atomicAdd(&lcnt[bk[j]], 1);
        }
    }
    __syncthreads();
    if (lcnt[t] > 0) lbase[t] = atomicAdd(&bcnt[t], lcnt[t]);
    __syncthreads();
#pragma unroll
    for (int j = 0; j < 16; ++j) {
        if (ok[j]) {
            int p = lbase[bk[j]] + atomicAdd(&lcur[bk[j]], 1);
            if (p < CAP) buckets[(size_t)bk[j] * CAP + p] = val[j];
        }
    }
}

// ---- shared gemm core (MFMA bf16, alpha fused; optional planar C) ----------
__device__ __forceinline__ void gemm_core(const ushort* __restrict__ A,
                                          const ushort* __restrict__ Bt,
                                          ushort* __restrict__ C,
                                          int M, int K, int Nc,
                                          const void* __restrict__ aS,
                                          const void* __restrict__ aD,
                                          float* __restrict__ alphaS,
                                          float* __restrict__ alphaD,
                                          int H, int f, int gx, int head,
                                          int planar) {
    int tid = threadIdx.x;
    int wave = tid >> 6, lane = tid & 63, quad = lane >> 4, l16 = lane & 15;
    int rbase = gx * 256 + wave * 64;
    int cbase = head * 64;
    floatx4 acc[4][4];
#pragma unroll
    for (int i = 0; i < 4; i++)
#pragma unroll
        for (int j = 0; j < 4; j++) acc[i][j] = (floatx4)0.f;

    for (int kb = 0; kb < K; kb += 32) {
        int k0 = kb + quad * 8;
        short8 a[4], b[4];
#pragma unroll
        for (int mt = 0; mt < 4; mt++) {
            int row = rbase + mt * 16 + l16;
            if (row >= M) row = M - 1;  // clamp; oob rows never stored
            a[mt] = *reinterpret_cast<const short8*>(A + (size_t)row * K + k0);
        }
#pragma unroll
        for (int nt = 0; nt < 4; nt++) {
            int col = cbase + nt * 16 + l16;
            b[nt] = *reinterpret_cast<const short8*>(Bt + (size_t)col * K + k0);
        }
#pragma unroll
        for (int mt = 0; mt < 4; mt++)
#pragma unroll
            for (int nt = 0; nt < 4; nt++)
                acc[mt][nt] = __builtin_amdgcn_mfma_f32_16x16x32_bf16(
                    a[mt], b[nt], acc[mt][nt], 0, 0, 0);
    }
    float asv[4], adv[4];
#pragma unroll
    for (int nt = 0; nt < 4; nt++) {
        int col = cbase + nt * 16 + l16;
        asv[nt] = load_in(aS, col, f);
        adv[nt] = load_in(aD, col, f);
    }
    // C/D layout: col = lane&15, row = quad*4 + reg   [m89-verified]
#pragma unroll
    for (int mt = 0; mt < 4; mt++) {
#pragma unroll
        for (int r = 0; r < 4; r++) {
            int row = rbase + mt * 16 + quad * 4 + r;
            float ps = 0.f, pd = 0.f;
#pragma unroll
            for (int nt = 0; nt < 4; nt++) {
                float w = acc[mt][nt][r];
                ps += w * asv[nt];
                pd += w * adv[nt];
            }
#pragma unroll
            for (int off = 8; off > 0; off >>= 1) {  // reduce over 16 col-lanes
                ps += __shfl_xor(ps, off, 16);
                pd += __shfl_xor(pd, off, 16);
            }
            if (row < M) {
                if (l16 == 0) {
                    alphaS[row * H + head] = ps;
                    alphaD[row * H + head] = pd;
                }
#pragma unroll
                for (int nt = 0; nt < 4; nt++) {
                    int col = cbase + nt * 16 + l16;
                    size_t caddr = planar
                        ? ((size_t)(col >> 7) * M + row) * 128 + (col & 127)
                        : (size_t)row * Nc + col;
                    C[caddr] = f2bf(acc[mt][nt][r]);
                }
            }
        }
    }
}

// ---- fused: gemm1 blocks [0, g1) + CSR pass-2 blocks [g1, g1+NB) -----------
__global__ __launch_bounds__(256) void gemm1_pass2_kernel(
        const ushort* __restrict__ A, const ushort* __restrict__ Bt,
        ushort* __restrict__ C, int M, int K, int Nc,
        const void* __restrict__ aS, const void* __restrict__ aD,
        float* __restrict__ alphaS, float* __restrict__ alphaD,
        const int* __restrict__ flags, int g1, int nbx,
        const int* __restrict__ bcnt, const unsigned int* __restrict__ buckets,
        int* __restrict__ offs, int* __restrict__ csr_src, int Nn) {
    __shared__ int part[256], sc[256], cur[256];
    int bid = blockIdx.x;
    int t = threadIdx.x;
    if (bid < g1) {
        gemm_core(A, Bt, C, M, K, Nc, aS, aD, alphaS, alphaD, 4, flags[0],
                  bid % nbx, bid / nbx, 1);
        return;
    }
    // ---- CSR pass 2: one block per 256-node bucket ----
    int b = bid - g1;
    part[t] = bcnt[t];
    __syncthreads();
#pragma unroll
    for (int off = 1; off < 256; off <<= 1) {   // inclusive scan of bucket sizes
        int v = (t >= off) ? part[t - off] : 0;
        __syncthreads();
        part[t] += v;
        __syncthreads();
    }
    int basepos = (b == 0) ? 0 : part[b - 1];
    int nEdges = min(bcnt[b], CAP);
    sc[t] = 0;
    __syncthreads();
    const unsigned int* bk = buckets + (size_t)b * CAP;
    for (int i = t; i < nEdges; i += 256)
        atomicAdd(&sc[bk[i] & 255], 1);
    __syncthreads();
    int mycount = sc[t];
    __syncthreads();
#pragma unroll
    for (int off = 1; off < 256; off <<= 1) {   // inclusive scan of node counts
        int v = (t >= off) ? sc[t - off] : 0;
        __syncthreads();
        sc[t] += v;
        __syncthreads();
    }
    int excl = sc[t] - mycount;
    int gnode = b * 256 + t;
    if (gnode <= Nn) offs[gnode] = basepos + excl;
    cur[t] = excl;
    __syncthreads();
    for (int i = t; i < nEdges; i += 256) {
        unsigned int v = bk[i];
        int p = atomicAdd(&cur[v & 255], 1);
        csr_src[basepos + p] = (int)(v >> 8);
    }
}

// ---- layer-2 gemm (H=1), standalone ---------------------------------------
__global__ __launch_bounds__(256) void gemm2_kernel(const ushort* __restrict__ A,
                                                    const ushort* __restrict__ Bt,
                                                    ushort* __restrict__ C,
                                                    int M, int K, int Nc,
                                                    const void* __restrict__ aS,
                                                    const void* __restrict__ aD,
                                                    float* __restrict__ alphaS,
                                                    float* __restrict__ alphaD,
                                                    const int* __restrict__ flags) {
    gemm_core(A, Bt, C, M, K, Nc, aS, aD, alphaS, alphaD, 1, flags[0],
              blockIdx.x, blockIdx.y, 0);
}

// ---- layer-1 aggregation, one plane (128 ch) per dispatch ------------------
// 1 wave/node, 2 edges/wave: half = lane>>5 processes edge e+half, 4 ch/lane.
// Halves combined via shfl_xor(32). Masked tail: a=-1e30 -> p=0.
__global__ __launch_bounds__(256) void gat_node1_pass(
        const int* __restrict__ csr_src, const int* __restrict__ offs,
        const float* __restrict__ asrc, const float* __restrict__ adst,
        const ushort* __restrict__ h1p, const void* __restrict__ b1,
        ushort* __restrict__ hmidb, int Nn, const int* __restrict__ flags,
        int plane) {
    int f = flags[0];
    int wave = threadIdx.x >> 6, lane = threadIdx.x & 63;
    int n = blockIdx.x * 4 + wave;
    if (n >= Nn) return;
    int half = lane >> 5, l5 = lane & 31;
    int head = plane * 2 + (l5 >> 4);
    float ad = adst[n * H1 + head];
    unsigned rowoff = (unsigned)(plane * Nn) * 128u + (unsigned)l5 * 4u;
    int beg = offs[n], end = offs[n + 1];
    float a0 = 0.f, a1 = 0.f, a2 = 0.f, a3 = 0.f, l = 0.f;

    int e = beg;
    while (e + 16 <= end) {           // 8 pairs, both halves valid
        int sj[8]; float aj[8]; uint2 vj[8];
#pragma unroll
        for (int j = 0; j < 8; ++j) sj[j] = csr_src[e + 2 * j + half];
#pragma unroll
        for (int j = 0; j < 8; ++j) {
            aj[j] = asrc[sj[j] * H1 + head];
            vj[j] = *(const uint2*)(h1p + rowoff + (unsigned)sj[j] * 128u);
        }
#pragma unroll
        for (int j = 0; j < 8; ++j) {
            float s = aj[j] + ad;
            s = fmaxf(s, 0.2f * s);              // leaky_relu 0.2
            float p = __expf(s);
            l += p;
            union { unsigned int i; float fl; } c0, c1, c2, c3;
            c0.i = vj[j].x << 16; c1.i = vj[j].x & 0xffff0000u;
            c2.i = vj[j].y << 16; c3.i = vj[j].y & 0xffff0000u;
            a0 += p * c0.fl; a1 += p * c1.fl;
            a2 += p * c2.fl; a3 += p * c3.fl;
        }
        e += 16;
    }
    if (e < end) {                    // masked tail (<16 edges = <8 pairs)
        int sj[8]; float aj[8]; uint2 vj[8];
#pragma unroll
        for (int j = 0; j < 8; ++j) {
            int ei = e + 2 * j + half;
            sj[j] = csr_src[ei < end ? ei : beg];
        }
#pragma unroll
        for (int j = 0; j < 8; ++j) {
            int ei = e + 2 * j + half;
            aj[j] = (ei < end) ? asrc[sj[j] * H1 + head] : -1e30f;
            vj[j] = *(const uint2*)(h1p + rowoff + (unsigned)sj[j] * 128u);
        }
#pragma unroll
        for (int j = 0; j < 8; ++j) {
            float s = aj[j] + ad;
            s = fmaxf(s, 0.2f * s);
            float p = __expf(s);                 // 0 for masked
            l += p;
            union { unsigned int i; float fl; } c0, c1, c2, c3;
            c0.i = vj[j].x << 16; c1.i = vj[j].x & 0xffff0000u;
            c2.i = vj[j].y << 16; c3.i = vj[j].y & 0xffff0000u;
            a0 += p * c0.fl; a1 += p * c1.fl;
            a2 += p * c2.fl; a3 += p * c3.fl;
        }
    }
    a0 += __shfl_xor(a0, 32); a1 += __shfl_xor(a1, 32);
    a2 += __shfl_xor(a2, 32); a3 += __shfl_xor(a3, 32);
    l  += __shfl_xor(l, 32);
    if (half == 0) {
        float inv = 1.f / (l + 1e-16f);
        int cb = plane * 128 + l5 * 4;
        float o0 = a0 * inv + load_in(b1, cb + 0, f);
        float o1 = a1 * inv + load_in(b1, cb + 1, f);
        float o2 = a2 * inv + load_in(b1, cb + 2, f);
        float o3 = a3 * inv + load_in(b1, cb + 3, f);
        o0 = o0 > 0.f ? o0 : __expf(o0) - 1.f;   // ELU
        o1 = o1 > 0.f ? o1 : __expf(o1) - 1.f;
        o2 = o2 > 0.f ? o2 : __expf(o2) - 1.f;
        o3 = o3 > 0.f ? o3 : __expf(o3) - 1.f;
        uint2 st;
        st.x = (unsigned int)f2bf(o0) | ((unsigned int)f2bf(o1) << 16);
        st.y = (unsigned int)f2bf(o2) | ((unsigned int)f2bf(o3) << 16);
        *(uint2*)(hmidb + (unsigned)n * 256u + (unsigned)cb) = st;
    }
}

// ---- layer-2 aggregation: 1 wave/node, 4 edges/wave (16 lanes each) --------
__global__ __launch_bounds__(256) void gat_node2(const int* __restrict__ csr_src,
                                                 const int* __restrict__ offs,
                                                 const float* __restrict__ asrc,
                                                 const float* __restrict__ adst,
                                                 const ushort* __restrict__ h2b,
                                                 const void* __restrict__ b2,
                                                 void* __restrict__ out, int Nn,
                                                 const int* __restrict__ flags) {
    int f = flags[0];
    int wave = threadIdx.x >> 6, lane = threadIdx.x & 63;
    int n = blockIdx.x * 4 + wave;
    if (n >= Nn) return;
    int q = lane >> 4, l4 = lane & 15;
    float ad = adst[n];
    int beg = offs[n], end = offs[n + 1];
    float a0 = 0.f, a1 = 0.f, a2 = 0.f, a3 = 0.f, l = 0.f;

    int e = beg;
    while (e + 16 <= end) {           // 4 quads, all valid
        int sj[4]; float aj[4]; uint2 vj[4];
#pragma unroll
        for (int j = 0; j < 4; ++j) sj[j] = csr_src[e + 4 * j + q];
#pragma unroll
        for (int j = 0; j < 4; ++j) {
            aj[j] = asrc[sj[j]];
            vj[j] = *(const uint2*)(h2b + (unsigned)sj[j] * 64u + (unsigned)l4 * 4u);
        }
#pragma unroll
        for (int j = 0; j < 4; ++j) {
            float s = aj[j] + ad;
            s = fmaxf(s, 0.2f * s);
            float p = __expf(s);
            l += p;
            union { unsigned int i; float fl; } c0, c1, c2, c3;
            c0.i = vj[j].x << 16; c1.i = vj[j].x & 0xffff0000u;
            c2.i = vj[j].y << 16; c3.i = vj[j].y & 0xffff0000u;
            a0 += p * c0.fl; a1 += p * c1.fl;
            a2 += p * c2.fl; a3 += p * c3.fl;
        }
        e += 16;
    }
    if (e < end) {                    // masked tail (<16 edges)
        int sj[4]; float aj[4]; uint2 vj[4];
#pragma unroll
        for (int j = 0; j < 4; ++j) {
            int ei = e + 4 * j + q;
            sj[j] = csr_src[ei < end ? ei : beg];
        }
#pragma unroll
        for (int j = 0; j < 4; ++j) {
            int ei = e + 4 * j + q;
            aj[j] = (ei < end) ? asrc[sj[j]] : -1e30f;
            vj[j] = *(const uint2*)(h2b + (unsigned)sj[j] * 64u + (unsigned)l4 * 4u);
        }
#pragma unroll
        for (int j = 0; j < 4; ++j) {
            float s = aj[j] + ad;
            s = fmaxf(s, 0.2f * s);
            float p = __expf(s);
            l += p;
            union { unsigned int i; float fl; } c0, c1, c2, c3;
            c0.i = vj[j].x << 16; c1.i = vj[j].x & 0xffff0000u;
            c2.i = vj[j].y << 16; c3.i = vj[j].y & 0xffff0000u;
            a0 += p * c0.fl; a1 += p * c1.fl;
            a2 += p * c2.fl; a3 += p * c3.fl;
        }
    }
#pragma unroll
    for (int off = 16; off <= 32; off <<= 1) {
        a0 += __shfl_xor(a0, off); a1 += __shfl_xor(a1, off);
        a2 += __shfl_xor(a2, off); a3 += __shfl_xor(a3, off);
        l  += __shfl_xor(l, off);
    }
    if (lane < 16) {
        float inv = 1.f / (l + 1e-16f);
        float o0 = a0 * inv + load_in(b2, l4 * 4 + 0, f);
        float o1 = a1 * inv + load_in(b2, l4 * 4 + 1, f);
        float o2 = a2 * inv + load_in(b2, l4 * 4 + 2, f);
        float o3 = a3 * inv + load_in(b2, l4 * 4 + 3, f);
        if (f) {
            float4 st; st.x = o0; st.y = o1; st.z = o2; st.w = o3;
            *(float4*)((float*)out + (unsigned)n * 64u + (unsigned)l4 * 4u) = st;
        } else {
            uint2 st;
            st.x = (unsigned int)f2bf(o0) | ((unsigned int)f2bf(o1) << 16);
            st.y = (unsigned int)f2bf(o2) | ((unsigned int)f2bf(o3) << 16);
            *(uint2*)((ushort*)out + (unsigned)n * 64u + (unsigned)l4 * 4u) = st;
        }
    }
}

extern "C" void kernel_launch(void* const* d_in, const int* in_sizes, int n_in,
                              void* d_out, int out_size, void* d_ws, size_t ws_size,
                              hipStream_t stream) {
    const void* x   = d_in[0];
    const void* ei  = d_in[1];
    const void* W1  = d_in[2];
    const void* as1 = d_in[3];
    const void* ad1 = d_in[4];
    const void* b1  = d_in[5];
    const void* W2  = d_in[6];
    const void* as2 = d_in[7];
    const void* ad2 = d_in[8];
    const void* b2  = d_in[9];

    const int Nn = in_sizes[0] / FIN;      // 50000
    const int E  = in_sizes[1] / 2;        // 1600000
    const int ET = E + Nn;
    const int NB = (Nn + 255) >> 8;        // 196 buckets

    char* ws = (char*)d_ws;
    size_t off = 0;
    auto alloc = [&](size_t bytes) {
        size_t o = off;
        off += (bytes + 255) & ~(size_t)255;
        return o;
    };
    ushort* xb    = (ushort*)(ws + alloc((size_t)Nn * FIN * 2));
    ushort* h1b   = (ushort*)(ws + alloc((size_t)Nn * FIN * 2));   // planar [2][Nn][128]
    ushort* hmidb = (ushort*)(ws + alloc((size_t)Nn * FIN * 2));
    ushort* h2b   = (ushort*)(ws + alloc((size_t)Nn * CH * 2));
    ushort* Wt1   = (ushort*)(ws + alloc((size_t)FIN * FIN * 2));
    ushort* Wt2   = (ushort*)(ws + alloc((size_t)CH * FIN * 2));
    float* as1f   = (float*)(ws + alloc((size_t)Nn * H1 * 4));
    float* ad1f   = (float*)(ws + alloc((size_t)Nn * H1 * 4));
    float* as2f   = (float*)(ws + alloc((size_t)Nn * 4));
    float* ad2f   = (float*)(ws + alloc((size_t)Nn * 4));
    int*   offs   = (int*)(ws + alloc((size_t)(Nn + 1) * 4));
    int*   csr    = (int*)(ws + alloc((size_t)ET * 4));
    unsigned int* buckets = (unsigned int*)(ws + alloc((size_t)256 * CAP * 4));
    int*   bcnt   = (int*)(ws + alloc(256 * 4));
    int*   flags  = (int*)(ws + alloc(256));
    (void)ws_size; (void)n_in; (void)out_size;

    probe_kernel<<<1, 256, 0, stream>>>((const ushort*)x, (const int*)ei, flags, bcnt);

    // fused prep (convert+transpose) | bucket pass 1
    int PB_conv = (Nn * FIN) / 2048;                       // 8 elem/thread
    int PB_tr   = (FIN * FIN + CH * FIN) / 256;            // 320
    int PB_bkt  = (ET + 4095) / 4096;
    prep_bucket_kernel<<<PB_conv + PB_tr + PB_bkt, 256, 0, stream>>>(
        x, W1, W2, xb, Wt1, Wt2, ei, bcnt, buckets,
        E, ET, Nn, flags, PB_conv, PB_conv + PB_tr);

    // fused: gemm1 (+alpha, planar C) and CSR pass 2
    int nbx = (Nn + 255) / 256;            // 196 row-blocks
    int g1 = nbx * H1;                     // 784 gemm blocks
    gemm1_pass2_kernel<<<g1 + NB, 256, 0, stream>>>(
        xb, Wt1, h1b, Nn, FIN, FIN, as1, ad1, as1f, ad1f,
        flags, g1, nbx, bcnt, buckets, offs, csr, Nn);

    // layer-1 aggregation: one dispatch per 128-ch plane (time-separated)
    gat_node1_pass<<<(Nn + 3) / 4, 256, 0, stream>>>(
        csr, offs, as1f, ad1f, h1b, b1, hmidb, Nn, flags, 0);
    gat_node1_pass<<<(Nn + 3) / 4, 256, 0, stream>>>(
        csr, offs, as1f, ad1f, h1b, b1, hmidb, Nn, flags, 1);

    // layer 2
    gemm2_kernel<<<dim3((Nn + 255) / 256, 1), 256, 0, stream>>>(
        hmidb, Wt2, h2b, Nn, FIN, CH, as2, ad2, as2f, ad2f, flags);
    gat_node2<<<(Nn + 3) / 4, 256, 0, stream>>>(csr, offs, as2f, ad2f, h2b, b2, d_out, Nn, flags);
}